// Round 5
// baseline (1978.031 us; speedup 1.0000x reference)
//
#include <hip/hip_runtime.h>
#include <hip/hip_bf16.h>
#include <stdint.h>

// Problem constants
#define Bb 16
#define Ss 2048
#define Dd 1024
#define Hh 1024
#define Rr 16
#define Mm 32768   // B*S

typedef __attribute__((ext_vector_type(4))) float f32x4;
typedef __attribute__((ext_vector_type(2))) float f32x2;
typedef __attribute__((ext_vector_type(8))) short bf16x8;

// RNE fp32 -> bf16 bits
__device__ __forceinline__ unsigned short f2bf(float f) {
    union { float f; uint32_t u; } c; c.f = f;
    uint32_t u = c.u + 0x7fffu + ((c.u >> 16) & 1u);
    return (unsigned short)(u >> 16);
}
__device__ __forceinline__ float bflo2f(uint32_t pair) {
    union { uint32_t u; float f; } c; c.u = pair << 16; return c.f;
}
__device__ __forceinline__ float bfhi2f(uint32_t pair) {
    union { uint32_t u; float f; } c; c.u = pair & 0xffff0000u; return c.f;
}

// async global->LDS, 16B per lane. LDS dest = uniform base + lane*16.
__device__ __forceinline__ void gld16(const void* gsrc, void* ldst) {
    __builtin_amdgcn_global_load_lds(
        (const __attribute__((address_space(1))) unsigned int*)gsrc,
        (__attribute__((address_space(3))) unsigned int*)ldst, 16, 0, 0);
}

// Raw workgroup barrier WITHOUT the vmcnt(0) drain __syncthreads carries.
// imm 0xC07F = vmcnt(63) expcnt(7) lgkmcnt(0)  [gfx9 encoding]
// Proven R2: keeps the global prefetch ring in flight across barriers.
__device__ __forceinline__ void softbar() {
    __asm volatile("" ::: "memory");
    __builtin_amdgcn_s_waitcnt(0xC07F);
    __builtin_amdgcn_s_barrier();
    __asm volatile("" ::: "memory");
}
// Intra-wave LDS handoff: drain lgkm so this wave's ds_write is readable
// by its own lanes. DS pipe is in-order per wave; no barrier needed.
__device__ __forceinline__ void ldsfence() {
    __asm volatile("" ::: "memory");
    __builtin_amdgcn_s_waitcnt(0xC07F);
    __asm volatile("" ::: "memory");
}

// ---------------------------------------------------------------------------
// Kernel 1: convert x, Wa, Wu to bf16 (flat, 4 elems/thread)
// ---------------------------------------------------------------------------
__global__ __launch_bounds__(256) void k_convert(
    const float* __restrict__ x, const float* __restrict__ Wa,
    const float* __restrict__ Wu,
    unsigned short* __restrict__ xb, unsigned short* __restrict__ Wab,
    unsigned short* __restrict__ Wub)
{
    long e = ((long)blockIdx.x * 256 + threadIdx.x) * 4;
    const long nx = (long)Mm * Dd;        // 33,554,432
    const long nw = (long)Hh * Dd;        // 1,048,576
    const float* src; unsigned short* dst; long o;
    if (e < nx)            { src = x;  dst = xb;  o = e; }
    else if (e < nx + nw)  { src = Wa; dst = Wab; o = e - nx; }
    else                   { src = Wu; dst = Wub; o = e - nx - nw; }
    float4 f = *(const float4*)(src + o);
    ushort4 r;
    r.x = f2bf(f.x); r.y = f2bf(f.y); r.z = f2bf(f.z); r.w = f2bf(f.w);
    *(ushort4*)(dst + o) = r;
}

// ---------------------------------------------------------------------------
// Kernel 2: C[M,1024] = Xb @ W^T (+bias, optional sigmoid), bf16 MFMA.
// Outputs bf16 (halves epilogue writes AND the scan's stream reads).
// ---------------------------------------------------------------------------
__global__ __launch_bounds__(256) void k_gemm(
    const unsigned short* __restrict__ Xb,   // [M, D] bf16 bits
    const unsigned short* __restrict__ Wab,  // [H, D]
    const unsigned short* __restrict__ Wub,  // [H, D]
    const float* __restrict__ ba, const float* __restrict__ bu,
    unsigned short* __restrict__ outA, unsigned short* __restrict__ outU)
{
    __shared__ short At[128 * 32];
    __shared__ short Bt[128 * 32];

    const int tid  = threadIdx.x;
    const int lane = tid & 63;
    const int wave = tid >> 6;
    const int bm = blockIdx.x;
    const int bn = blockIdx.y;
    const int region = bn >> 3;            // 0: a, 1: u_in
    const int nbase = (bn & 7) * 128;

    const short* Ag = (const short*)Xb;
    const short* Bg = (const short*)(region ? Wub : Wab);
    const float* bias = region ? bu : ba;
    unsigned short* outp = region ? outU : outA;

    const int wm = wave & 1, wn = wave >> 1;
    const int srow = lane >> 2, sseg = lane & 3;   // staging: 4 lanes/row
    const int mrow = lane & 15, kb = lane >> 4;    // fragment lane mapping

    f32x4 acc[4][4] = {};

    for (int kt = 0; kt < 32; ++kt) {
        __syncthreads();
        const int k0 = kt * 32;
        #pragma unroll
        for (int p = 0; p < 2; ++p) {
            const int row = p * 64 + wave * 16 + srow;
            const short* ga = Ag + (long)(bm * 128 + row) * Dd + k0 + sseg * 8;
            gld16((const void*)ga, (void*)&At[p * 2048 + wave * 512]);
            const short* gb = Bg + (long)(nbase + row) * Dd + k0 + sseg * 8;
            gld16((const void*)gb, (void*)&Bt[p * 2048 + wave * 512]);
        }
        __syncthreads();

        bf16x8 af[4], bq[4];
        #pragma unroll
        for (int i = 0; i < 4; ++i) {
            af[i] = *(const bf16x8*)&At[(wm * 64 + i * 16 + mrow) * 32 + kb * 8];
            bq[i] = *(const bf16x8*)&Bt[(wn * 64 + i * 16 + mrow) * 32 + kb * 8];
        }
        #pragma unroll
        for (int i = 0; i < 4; ++i)
            #pragma unroll
            for (int j = 0; j < 4; ++j)
                acc[i][j] = __builtin_amdgcn_mfma_f32_16x16x32_bf16(
                    af[i], bq[j], acc[i][j], 0, 0, 0);
    }

    // Epilogue: C/D layout col=lane&15, row=(lane>>4)*4+reg (m89-verified)
    const int col = lane & 15, rq = lane >> 4;
    #pragma unroll
    for (int j = 0; j < 4; ++j) {
        const int n = nbase + wn * 64 + j * 16 + col;
        const float bv = bias[n];
        #pragma unroll
        for (int i = 0; i < 4; ++i) {
            const int mb = bm * 128 + wm * 64 + i * 16 + rq * 4;
            #pragma unroll
            for (int r = 0; r < 4; ++r) {
                float vv = acc[i][j][r] + bv;
                if (region == 0) vv = 1.0f / (1.0f + __expf(-vv));
                outp[(long)(mb + r) * Hh + n] = f2bf(vv);
            }
        }
    }
}

// ---------------------------------------------------------------------------
// Kernel 3: g[M,16] = x @ Wg^T + bg (fp32, tiny N)
// ---------------------------------------------------------------------------
__global__ __launch_bounds__(256) void k_g(
    const float* __restrict__ x, const float* __restrict__ Wg,
    const float* __restrict__ bg, float* __restrict__ g)
{
    const int tid = threadIdx.x;
    const int r = tid & 15, ml = tid >> 4;
    const long m = (long)blockIdx.x * 16 + ml;
    const float4* xr = (const float4*)(x + m * Dd);
    const float4* wr = (const float4*)(Wg + (long)r * Dd);
    float acc = 0.0f;
    #pragma unroll 4
    for (int k = 0; k < Dd / 4; ++k) {
        float4 a = xr[k], b = wr[k];
        acc = fmaf(a.x, b.x, acc); acc = fmaf(a.y, b.y, acc);
        acc = fmaf(a.z, b.z, acc); acc = fmaf(a.w, b.w, acc);
    }
    g[m * Rr + r] = acc + bg[r];
}

// ---------------------------------------------------------------------------
// Kernel 4: sequential scan. 16 blocks x 512 threads (8 waves); thread owns
// state pair h = {2t, 2t+1}. TWO barriers/step (R4's 3 bars x ~300 cyc were
// ~2/3 of the step):
//  A: wave w covers h in [128w,128w+128); lane (ra=lane&15, sub=lane>>4)
//     does 16 pk_fma over its 32 h's; 2 shfl hops; lanes<16 write
//     cacc[ra][w].               -> bar1
//  C: EVERY lane redundantly computes q[ra] = g*sum_w cacc[ra][w]
//     (2xb128 + 6 ops), writes per-wave qw[wave][ra], intra-wave
//     lgkm fence (NO barrier - DS pipe is in-order per wave), reads
//     qw[wave][0..15] broadcast, 16 pk_fma vs U, packed diag update,
//     b64 state write.           -> bar2
// softbar never drains vmcnt: depth-4 global prefetch ring stays in
// flight. a/u streams bf16, one dword = the thread's {2t,2t+1} pair.
// ---------------------------------------------------------------------------
__global__ __launch_bounds__(512) void k_scan(
    const unsigned short* __restrict__ a,    // [B,S,H] bf16
    const unsigned short* __restrict__ uin,  // [B,S,H] bf16
    const float* __restrict__ g,    // [B,S,R]
    const float* __restrict__ u,    // [H,R]
    const float* __restrict__ v,    // [H,R]
    float* __restrict__ out)        // [B,H]
{
    __shared__ __align__(16) float sbf[Hh];        // fp32 state, 4 KB
    __shared__ __align__(16) float cacc[16 * 12];  // [r][w], stride 12
    __shared__ __align__(16) float qw[8 * 20];     // per-wave q, stride 20 (80B, 16B-aligned)

    const int tid  = threadIdx.x;
    const int lane = tid & 63;
    const int wave = tid >> 6;       // 0..7
    const int sub  = lane >> 4;      // 0..3
    const int ra   = lane & 15;      // r owned
    const int b = blockIdx.x;
    const int h0 = 2 * tid;

    // phase-A consts: pairs v[hA+2k][ra], v[hA+2k+1][ra], hA = 128*wave+32*sub
    const int hA = wave * 128 + sub * 32;
    f32x2 vr2[16];
    #pragma unroll
    for (int k = 0; k < 16; ++k) {
        f32x2 t;
        t.x = v[(hA + 2 * k + 0) * Rr + ra];
        t.y = v[(hA + 2 * k + 1) * Rr + ra];
        vr2[k] = t;
    }
    // phase-C consts: ur2[r] = {u[h0][r], u[h0+1][r]}
    f32x2 ur2[16];
    #pragma unroll
    for (int r = 0; r < 16; ++r) {
        f32x2 t; t.x = u[h0 * Rr + r]; t.y = u[(h0 + 1) * Rr + r];
        ur2[r] = t;
    }

    // streams: one dword = bf16 pair {2t, 2t+1}
    const uint32_t* ap = (const uint32_t*)(a   + (long)b * Ss * Hh) + tid;
    const uint32_t* up = (const uint32_t*)(uin + (long)b * Ss * Hh) + tid;
    const float*    gp = g + (long)b * Ss * Rr + ra;   // all lanes load (16-way dup)

    uint32_t pa[4], pu[4]; float pg[4];
    #pragma unroll
    for (int t = 0; t < 4; ++t) {
        pa[t] = ap[t * (Hh / 2)]; pu[t] = up[t * (Hh / 2)]; pg[t] = gp[t * Rr];
    }
    ap += 4 * (Hh / 2); up += 4 * (Hh / 2); gp += 4 * Rr;

    f32x2 s2; s2.x = 0.0f; s2.y = 0.0f;
    *(f32x2*)&sbf[h0] = s2;
    __syncthreads();

    const f32x4* spA = (const f32x4*)&sbf[hA];
    const int caccw = 12 * ra + wave;
    const f32x4* crow = (const f32x4*)&cacc[12 * ra];
    float* qslot = &qw[20 * wave + ra];
    const f32x4* qrow = (const f32x4*)&qw[20 * wave];

#define STEP(R, PF) do {                                                    \
    /* A: partial for r=ra over 32 h's (16 packed fma) */                   \
    f32x4 t0 = spA[0], t1 = spA[1], t2 = spA[2], t3 = spA[3];               \
    f32x4 t4 = spA[4], t5 = spA[5], t6 = spA[6], t7 = spA[7];               \
    f32x2 p2 = t0.xy * vr2[0];                                              \
    p2 += t0.zw * vr2[1];  p2 += t1.xy * vr2[2];  p2 += t1.zw * vr2[3];     \
    p2 += t2.xy * vr2[4];  p2 += t2.zw * vr2[5];  p2 += t3.xy * vr2[6];     \
    p2 += t3.zw * vr2[7];  p2 += t4.xy * vr2[8];  p2 += t4.zw * vr2[9];     \
    p2 += t5.xy * vr2[10]; p2 += t5.zw * vr2[11]; p2 += t6.xy * vr2[12];    \
    p2 += t6.zw * vr2[13]; p2 += t7.xy * vr2[14]; p2 += t7.zw * vr2[15];    \
    float part = p2.x + p2.y;                                               \
    part += __shfl_xor(part, 16);                                           \
    part += __shfl_xor(part, 32);                                           \
    if (lane < 16) cacc[caccw] = part;                                      \
    softbar(); /* bar1 */                                                   \
    /* C: every lane: q[ra] from cacc row, per-wave handoff, update pair */ \
    f32x4 c0 = crow[0], c1 = crow[1];                                       \
    f32x4 cs = c0 + c1;                                                     \
    float q_own = pg[R] * ((cs.x + cs.y) + (cs.z + cs.w));                  \
    if (sub == 0) *qslot = q_own;                                           \
    ldsfence(); /* intra-wave visibility, no barrier */                     \
    f32x4 q0 = qrow[0], q1 = qrow[1], q2 = qrow[2], q3 = qrow[3];           \
    f32x2 lr2 = f32x2{q0.x, q0.x} * ur2[0];                                 \
    lr2 += f32x2{q0.y, q0.y} * ur2[1];  lr2 += f32x2{q0.z, q0.z} * ur2[2];  \
    lr2 += f32x2{q0.w, q0.w} * ur2[3];  lr2 += f32x2{q1.x, q1.x} * ur2[4];  \
    lr2 += f32x2{q1.y, q1.y} * ur2[5];  lr2 += f32x2{q1.z, q1.z} * ur2[6];  \
    lr2 += f32x2{q1.w, q1.w} * ur2[7];  lr2 += f32x2{q2.x, q2.x} * ur2[8];  \
    lr2 += f32x2{q2.y, q2.y} * ur2[9];  lr2 += f32x2{q2.z, q2.z} * ur2[10]; \
    lr2 += f32x2{q2.w, q2.w} * ur2[11]; lr2 += f32x2{q3.x, q3.x} * ur2[12]; \
    lr2 += f32x2{q3.y, q3.y} * ur2[13]; lr2 += f32x2{q3.z, q3.z} * ur2[14]; \
    lr2 += f32x2{q3.w, q3.w} * ur2[15];                                     \
    f32x2 av; av.x = bflo2f(pa[R]); av.y = bfhi2f(pa[R]);                   \
    f32x2 uv; uv.x = bflo2f(pu[R]); uv.y = bfhi2f(pu[R]);                   \
    s2 = av * s2 + (uv + lr2);                                              \
    *(f32x2*)&sbf[h0] = s2;                                                 \
    if (PF) {                                                               \
        pa[R] = *ap; ap += Hh / 2;                                          \
        pu[R] = *up; up += Hh / 2;                                          \
        pg[R] = *gp; gp += Rr;                                              \
    }                                                                       \
    softbar(); /* bar2 */                                                   \
} while (0)

    for (int t4 = 0; t4 < Ss / 4 - 1; ++t4) {
        STEP(0, 1); STEP(1, 1); STEP(2, 1); STEP(3, 1);
    }
    STEP(0, 0); STEP(1, 0); STEP(2, 0); STEP(3, 0);
#undef STEP

    *(f32x2*)&out[(long)b * Hh + h0] = s2;
}

// ---------------------------------------------------------------------------
extern "C" void kernel_launch(void* const* d_in, const int* in_sizes, int n_in,
                              void* d_out, int out_size, void* d_ws, size_t ws_size,
                              hipStream_t stream)
{
    const float* x  = (const float*)d_in[0];
    const float* Wa = (const float*)d_in[1];
    const float* ba = (const float*)d_in[2];
    const float* Wg = (const float*)d_in[3];
    const float* bg = (const float*)d_in[4];
    const float* Wu = (const float*)d_in[5];
    const float* bu = (const float*)d_in[6];
    const float* u  = (const float*)d_in[7];
    const float* v  = (const float*)d_in[8];
    float* out = (float*)d_out;

    char* ws = (char*)d_ws;
    unsigned short* xb   = (unsigned short*)(ws);                // 67,108,864 B
    unsigned short* Wab  = (unsigned short*)(ws + 67108864);     //  2,097,152 B
    unsigned short* Wub  = (unsigned short*)(ws + 69206016);     //  2,097,152 B
    unsigned short* abuf = (unsigned short*)(ws + 71303168);     // 67,108,864 B (bf16)
    unsigned short* ubuf = (unsigned short*)(ws + 138412032);    // 67,108,864 B (bf16)
    float*          gbuf = (float*)(ws + 205520896);             //  2,097,152 B

    hipLaunchKernelGGL(k_convert, dim3(34816), dim3(256), 0, stream,
                       x, Wa, Wu, xb, Wab, Wub);
    hipLaunchKernelGGL(k_gemm, dim3(256, 16), dim3(256), 0, stream,
                       xb, Wab, Wub, ba, bu, abuf, ubuf);
    hipLaunchKernelGGL(k_g, dim3(2048), dim3(256), 0, stream,
                       x, Wg, bg, gbuf);
    hipLaunchKernelGGL(k_scan, dim3(Bb), dim3(512), 0, stream,
                       abuf, ubuf, gbuf, u, v, out);
}